// Round 12
// baseline (82.707 us; speedup 1.0000x reference)
//
#include <hip/hip_runtime.h>
#include <math.h>

// Problem constants
#define B_  32
#define S_  2048
#define D_  512
#define A_  256
#define BS_ (B_ * S_)

// ws layout (float offsets)
#define WEFF_OFF  0                   // 256 floats
#define DEC_OFF   256                 // B*A = 8192
#define EPART_OFF 8448                // B*S = 65536 floats
#define CTX_OFF   (8448 + BS_)        // cpart 16*B*D; reused as W16 first

typedef _Float16 f16x8 __attribute__((ext_vector_type(8)));
typedef __fp16   fp16x2 __attribute__((ext_vector_type(2)));
typedef _Float16 half4 __attribute__((ext_vector_type(4)));
typedef float floatx4 __attribute__((ext_vector_type(4)));

__device__ __forceinline__ void glds16(const void* g, void* l) {
    __builtin_amdgcn_global_load_lds(
        (const __attribute__((address_space(1))) void*)g,
        (__attribute__((address_space(3))) void*)l, 16, 0, 0);
}

// ---------------------------------------------------------------------------
// Merged prep: block 0 = weff, blocks 1..32 = dec_term, blocks 33..160 = W->f16
__global__ void ma_prep_kernel(const float* __restrict__ v_w,
                               const float* __restrict__ v_g,
                               const float* __restrict__ dec,
                               const float* __restrict__ V,
                               const float* __restrict__ bvec,
                               const float* __restrict__ W,
                               _Float16* __restrict__ W16,
                               float* __restrict__ ws) {
    __shared__ float sh[D_];
    const int bid = blockIdx.x, t = threadIdx.x;
    if (bid == 0) {
        float v = v_w[t];
        float sq = v * v;
        #pragma unroll
        for (int off = 32; off > 0; off >>= 1) sq += __shfl_down(sq, off, 64);
        if ((t & 63) == 0) sh[t >> 6] = sq;
        __syncthreads();
        float n2 = sh[0] + sh[1] + sh[2] + sh[3];
        ws[WEFF_OFF + t] = v_g[0] * v / sqrtf(n2);
    } else if (bid <= B_) {
        const int b = bid - 1;
        sh[t]       = dec[b * D_ + t];
        sh[t + 256] = dec[b * D_ + 256 + t];
        __syncthreads();
        const float4* Vr = (const float4*)(V + (size_t)t * D_);
        float acc = 0.f;
        #pragma unroll 4
        for (int k = 0; k < D_ / 4; ++k) {
            float4 v4 = Vr[k];
            acc = fmaf(v4.x, sh[4*k+0], acc);
            acc = fmaf(v4.y, sh[4*k+1], acc);
            acc = fmaf(v4.z, sh[4*k+2], acc);
            acc = fmaf(v4.w, sh[4*k+3], acc);
        }
        ws[DEC_OFF + b * A_ + t] = acc + bvec[t];
    } else {
        int i = (bid - (B_ + 1)) * 256 + t;
        float4 v = ((const float4*)W)[i];
        half4 h;
        h[0] = (_Float16)v.x; h[1] = (_Float16)v.y;
        h[2] = (_Float16)v.z; h[3] = (_Float16)v.w;
        ((half4*)W16)[i] = h;
    }
}

// ---------------------------------------------------------------------------
// Energy, counted-vmcnt 2-phase template (T3/T4-lite + T14):
// Block = 128 rows x 256 a-cols, K=512, BK=64, 8 K-tiles fully unrolled.
// 8 waves (2 wm x 4 wn), each 64x64 via 4x4 frags of 16x16x32 f16, 2 k-sub.
// A: global->reg (issued 2 tiles ahead) -> cvt_pkrtz -> swizzled ds_write late.
// B: glds dbuf, pre-swizzled source. One barrier/tile; vmcnt(4) steady (never
// 0 until tail) so A(t+2) stays in flight across barriers. setprio on MFMA.
// LDS: A 2x16KB (f16) + B 2x32KB = 96 KB -> 1 block/CU, 2 waves/SIMD.
#define A0OFF 0
#define A1OFF 16384
#define B0OFF 32768
#define B1OFF 65536
__global__ __launch_bounds__(512, 2) void ma_energy_mfma(
        const float* __restrict__ enc,
        const _Float16* __restrict__ W16,
        const float* __restrict__ ws_in,
        float* __restrict__ energy) {
    __shared__ __align__(16) char smem[98304];

    const int t  = threadIdx.x;
    const int bx = blockIdx.x;             // 512 tiles of 128 rows
    const size_t R0 = (size_t)bx * 128;
    const int batch = bx >> 4;             // 16 tiles per batch

    const int lane = t & 63, wid = t >> 6;
    const int wm = wid >> 2, wn = wid & 3;
    const int fr = lane & 15, kq = lane >> 4;

    // A stage: thread -> row ar (4 thr/row), 16 f32 (4 float4) at q*16
    const int ar = t >> 2, aq = t & 3;
    const float* Ag = enc + (R0 + (size_t)ar) * D_ + aq * 16;
    // swizzled ds_write slots (involution c ^ (row&7))
    const int aws0 = ((2 * aq)     ^ (ar & 7)) * 16;   // bytes
    const int aws1 = ((2 * aq + 1) ^ (ar & 7)) * 16;

    // B glds: 4 ops, op j: slot p = j*512+t -> row p>>3, chunk p&7 (src pre-swz)
    // frag-read chunk slots (row&7 == fr&7 for all frag rows)
    const int sl0 = (kq     ^ (fr & 7)) * 16;   // ks=0, bytes
    const int sl1 = ((4+kq) ^ (fr & 7)) * 16;   // ks=1

    floatx4 acc[4][4];
    #pragma unroll
    for (int m = 0; m < 4; ++m)
        #pragma unroll
        for (int n = 0; n < 4; ++n) acc[m][n] = (floatx4)0.f;

    float4 a0r[4], a1r[4];   // two named A reg sets (rule #20: static only)

#define STAGE_B(kt, boff) do { \
        _Pragma("unroll") \
        for (int j = 0; j < 4; ++j) { \
            const int p = j * 512 + t; \
            const int row = p >> 3, c = p & 7; \
            glds16(W16 + (size_t)row * D_ + (kt) * 64 + ((c ^ (row & 7)) * 8), \
                   smem + (boff) + p * 16); \
        } } while (0)

#define LOADA(dst, kt) do { \
        _Pragma("unroll") \
        for (int j = 0; j < 4; ++j) \
            dst[j] = *(const float4*)(Ag + (kt) * 64 + j * 4); \
    } while (0)

#define CVTW(src, aoff) do { \
        union { fp16x2 h2[4]; f16x8 v; } u0, u1; \
        u0.h2[0] = __builtin_amdgcn_cvt_pkrtz(src[0].x, src[0].y); \
        u0.h2[1] = __builtin_amdgcn_cvt_pkrtz(src[0].z, src[0].w); \
        u0.h2[2] = __builtin_amdgcn_cvt_pkrtz(src[1].x, src[1].y); \
        u0.h2[3] = __builtin_amdgcn_cvt_pkrtz(src[1].z, src[1].w); \
        u1.h2[0] = __builtin_amdgcn_cvt_pkrtz(src[2].x, src[2].y); \
        u1.h2[1] = __builtin_amdgcn_cvt_pkrtz(src[2].z, src[2].w); \
        u1.h2[2] = __builtin_amdgcn_cvt_pkrtz(src[3].x, src[3].y); \
        u1.h2[3] = __builtin_amdgcn_cvt_pkrtz(src[3].z, src[3].w); \
        *(f16x8*)(smem + (aoff) + ar * 128 + aws0) = u0.v; \
        *(f16x8*)(smem + (aoff) + ar * 128 + aws1) = u1.v; \
    } while (0)

#define COMPUTE(aoff, boff) do { \
        const char* abase = smem + (aoff) + (wm * 64 + fr) * 128; \
        const char* bbase = smem + (boff) + (wn * 64 + fr) * 128; \
        _Pragma("unroll") \
        for (int ks = 0; ks < 2; ++ks) { \
            const int sl = ks ? sl1 : sl0; \
            f16x8 af[4], bf[4]; \
            _Pragma("unroll") \
            for (int m = 0; m < 4; ++m) af[m] = *(const f16x8*)(abase + m * 2048 + sl); \
            _Pragma("unroll") \
            for (int n = 0; n < 4; ++n) bf[n] = *(const f16x8*)(bbase + n * 2048 + sl); \
            __builtin_amdgcn_s_setprio(1); \
            _Pragma("unroll") \
            for (int m = 0; m < 4; ++m) \
                _Pragma("unroll") \
                for (int n = 0; n < 4; ++n) \
                    acc[m][n] = __builtin_amdgcn_mfma_f32_16x16x32_f16(af[m], bf[n], acc[m][n], 0, 0, 0); \
            __builtin_amdgcn_s_setprio(0); \
        } } while (0)

#define WAITV(n) asm volatile("s_waitcnt vmcnt(" #n ")" ::: "memory")
#define ENDTILE  do { \
        asm volatile("s_waitcnt lgkmcnt(0)" ::: "memory"); \
        __builtin_amdgcn_s_barrier(); \
        __builtin_amdgcn_sched_barrier(0); } while (0)

    // ---- prologue: queue = B0(4) A0(4) A1(4) ----
    STAGE_B(0, B0OFF);
    LOADA(a0r, 0);
    LOADA(a1r, 1);
    WAITV(4);                       // retire B0+A0; A1 in flight
    __builtin_amdgcn_sched_barrier(0);
    CVTW(a0r, A0OFF);
    ENDTILE;

    // ---- 8 K-tiles, one barrier each, counted vmcnt ----
    // t=0
    STAGE_B(1, B1OFF); LOADA(a0r, 2);
    COMPUTE(A0OFF, B0OFF);
    WAITV(4); __builtin_amdgcn_sched_barrier(0);   // A1+B1 done; A2 in flight
    CVTW(a1r, A1OFF); ENDTILE;
    // t=1
    STAGE_B(2, B0OFF); LOADA(a1r, 3);
    COMPUTE(A1OFF, B1OFF);
    WAITV(4); __builtin_amdgcn_sched_barrier(0);
    CVTW(a0r, A0OFF); ENDTILE;
    // t=2
    STAGE_B(3, B1OFF); LOADA(a0r, 4);
    COMPUTE(A0OFF, B0OFF);
    WAITV(4); __builtin_amdgcn_sched_barrier(0);
    CVTW(a1r, A1OFF); ENDTILE;
    // t=3
    STAGE_B(4, B0OFF); LOADA(a1r, 5);
    COMPUTE(A1OFF, B1OFF);
    WAITV(4); __builtin_amdgcn_sched_barrier(0);
    CVTW(a0r, A0OFF); ENDTILE;
    // t=4
    STAGE_B(5, B1OFF); LOADA(a0r, 6);
    COMPUTE(A0OFF, B0OFF);
    WAITV(4); __builtin_amdgcn_sched_barrier(0);
    CVTW(a1r, A1OFF); ENDTILE;
    // t=5
    STAGE_B(6, B0OFF); LOADA(a1r, 7);
    COMPUTE(A1OFF, B1OFF);
    WAITV(4); __builtin_amdgcn_sched_barrier(0);
    CVTW(a0r, A0OFF); ENDTILE;
    // t=6 (tail: no more A loads)
    STAGE_B(7, B1OFF);
    COMPUTE(A0OFF, B0OFF);
    WAITV(0); __builtin_amdgcn_sched_barrier(0);   // A7+B7 done, queue empty
    CVTW(a1r, A1OFF); ENDTILE;
    // t=7
    COMPUTE(A1OFF, B1OFF);
    __syncthreads();                // before red aliases A-buf 0

#undef STAGE_B
#undef LOADA
#undef CVTW
#undef COMPUTE
#undef WAITV
#undef ENDTILE

    // epilogue: tanh + weighted reduce over all 256 a-cols
    float* const red = (float*)smem;       // [4][128], aliases A buffers
    const float* weff  = ws_in + WEFF_OFF;
    const float* dterm = ws_in + DEC_OFF + batch * A_;
    float wj[4], dj[4];
    #pragma unroll
    for (int n = 0; n < 4; ++n) {
        int a = wn * 64 + n * 16 + fr;
        wj[n] = weff[a];
        dj[n] = dterm[a];
    }
    #pragma unroll
    for (int m = 0; m < 4; ++m) {
        #pragma unroll
        for (int r = 0; r < 4; ++r) {
            float v = 0.f;
            #pragma unroll
            for (int n = 0; n < 4; ++n) {
                float x = acc[m][n][r] + dj[n];
                float e = __expf(2.f * x);
                v += (1.f - 2.f / (e + 1.f)) * wj[n];   // tanh(x)
            }
            #pragma unroll
            for (int mask = 1; mask < 16; mask <<= 1)
                v += __shfl_xor(v, mask, 64);
            if (fr == 0)
                red[wn * 128 + wm * 64 + m * 16 + (kq << 2) + r] = v;
        }
    }
    __syncthreads();
    if (t < 128)
        energy[R0 + t] = red[t] + red[128 + t] + red[256 + t] + red[384 + t];
}

// ---------------------------------------------------------------------------
// Monotonic recurrence as a stable affine scan:
//   T_j = a_j * T_{j-1} + prev_j,  a_j = clip(1-p_j, 1e-10, 1),  alpha_j = p_j*T_j
__global__ void ma_scan_kernel(const float* __restrict__ energy,
                               const float* __restrict__ noise,
                               const float* __restrict__ prev,
                               const float* __restrict__ v_bias,
                               const float* __restrict__ r,
                               float* __restrict__ alpha_out) {
    int b = blockIdx.x, t = threadIdx.x;   // 256 threads x 8 elems
    const float bias = v_bias[0] + r[0];
    int base = b * S_ + t * 8;
    float p[8], av[8], bv[8];
    #pragma unroll
    for (int i = 0; i < 8; ++i) {
        float e = energy[base + i] + bias + noise[base + i];
        float pi = 1.f / (1.f + expf(-e));
        p[i]  = pi;
        av[i] = fmaxf(1.f - pi, 1e-10f);
        bv[i] = prev[base + i];
    }
    float Ai = 1.f, Bi = 0.f;
    #pragma unroll
    for (int i = 0; i < 8; ++i) { Bi = av[i] * Bi + bv[i]; Ai *= av[i]; }
    int lane = t & 63;
    #pragma unroll
    for (int off = 1; off < 64; off <<= 1) {
        float Ap = __shfl_up(Ai, off, 64);
        float Bp = __shfl_up(Bi, off, 64);
        if (lane >= off) { Bi = Ai * Bp + Bi; Ai = Ai * Ap; }
    }
    __shared__ float wA[4], wB[4];
    int w = t >> 6;
    if (lane == 63) { wA[w] = Ai; wB[w] = Bi; }
    __syncthreads();
    float Ax = __shfl_up(Ai, 1, 64);
    float Bx = __shfl_up(Bi, 1, 64);
    if (lane == 0) { Ax = 1.f; Bx = 0.f; }
    float PwA = 1.f, PwB = 0.f;
    for (int q = 0; q < w; ++q) { PwB = wA[q] * PwB + wB[q]; PwA *= wA[q]; }
    float T = Ax * PwB + Bx;
    #pragma unroll
    for (int i = 0; i < 8; ++i) {
        T = av[i] * T + bv[i];
        alpha_out[base + i] = p[i] * T;
    }
}

// ---------------------------------------------------------------------------
// context partials over s-chunks of 128, float4 loads; cpart = 1 MB (L2-fit)
__global__ void ma_ctxpart_kernel(const float* __restrict__ enc,
                                  const float* __restrict__ alpha,
                                  float* __restrict__ cpart) {
    int b = blockIdx.x, sc = blockIdx.y, t = threadIdx.x;   // (32,16) x 256
    const int sp = t >> 7;          // row parity
    const int d4 = t & 127;         // float4 column
    const float4* e = (const float4*)(enc + ((size_t)b * S_ + sc * 128) * D_);
    const float* al = alpha + b * S_ + sc * 128;
    float4 acc = {0.f, 0.f, 0.f, 0.f};
    #pragma unroll 4
    for (int s = sp; s < 128; s += 2) {
        float a = al[s];
        float4 v = e[(size_t)s * 128 + d4];
        acc.x = fmaf(v.x, a, acc.x);
        acc.y = fmaf(v.y, a, acc.y);
        acc.z = fmaf(v.z, a, acc.z);
        acc.w = fmaf(v.w, a, acc.w);
    }
    __shared__ float4 sh[128];
    if (sp == 1) sh[d4] = acc;
    __syncthreads();
    if (sp == 0) {
        float4 o = sh[d4];
        acc.x += o.x; acc.y += o.y; acc.z += o.z; acc.w += o.w;
        ((float4*)(cpart + ((size_t)(sc * B_ + b)) * D_))[d4] = acc;
    }
}

// 32 blocks x 512 thr: each thread one d, 16 coalesced partials
__global__ void ma_ctxreduce_kernel(const float* __restrict__ cpart,
                                    float* __restrict__ ctx) {
    int b = blockIdx.x, d = threadIdx.x;   // 512 threads
    float s = 0.f;
    #pragma unroll
    for (int q = 0; q < 16; ++q) s += cpart[((size_t)(q * B_ + b)) * D_ + d];
    ctx[b * D_ + d] = s;
}

// ---------------------------------------------------------------------------
extern "C" void kernel_launch(void* const* d_in, const int* in_sizes, int n_in,
                              void* d_out, int out_size, void* d_ws, size_t ws_size,
                              hipStream_t stream) {
    const float* enc    = (const float*)d_in[0];
    const float* dec    = (const float*)d_in[1];
    const float* prev   = (const float*)d_in[2];
    const float* noise  = (const float*)d_in[3];
    const float* W      = (const float*)d_in[4];
    const float* V      = (const float*)d_in[5];
    const float* bvec   = (const float*)d_in[6];
    const float* v_w    = (const float*)d_in[7];
    const float* v_g    = (const float*)d_in[8];
    const float* v_bias = (const float*)d_in[9];
    const float* r      = (const float*)d_in[10];

    float* out = (float*)d_out;             // [0:16384) context, [16384:81920) alpha
    float* ws  = (float*)d_ws;
    float* alpha = out + B_ * D_;
    _Float16* W16 = (_Float16*)(ws + CTX_OFF);   // region reused by cpart later

    ma_prep_kernel<<<1 + B_ + 128, 256, 0, stream>>>(v_w, v_g, dec, V, bvec, W, W16, ws);
    ma_energy_mfma<<<512, 512, 0, stream>>>(enc, W16, ws, ws + EPART_OFF);
    ma_scan_kernel<<<B_, 256, 0, stream>>>(ws + EPART_OFF, noise, prev, v_bias, r, alpha);
    dim3 gc(B_, 16);
    ma_ctxpart_kernel<<<gc, 256, 0, stream>>>(enc, alpha, ws + CTX_OFF);
    ma_ctxreduce_kernel<<<B_, 512, 0, stream>>>(ws + CTX_OFF, out);
}